// Round 1
// baseline (311.194 us; speedup 1.0000x reference)
//
#include <hip/hip_runtime.h>

#define BATCH 4
#define SEQ   2048
#define EMBED 1024
#define HEADS 16
#define HDIM  64
#define NTOK  (BATCH*SEQ)

typedef __attribute__((ext_vector_type(8)))  short short8;   // 8 bf16 = MFMA A/B frag
typedef __attribute__((ext_vector_type(4)))  float f32x4;    // 16x16 C frag
typedef __attribute__((ext_vector_type(16))) float f32x16;   // 32x32 C frag

static __device__ __forceinline__ unsigned short f2bf(float f) {
    union { float f; unsigned u; } v; v.f = f;
    return (unsigned short)((v.u + 0x7FFFu + ((v.u >> 16) & 1u)) >> 16);  // RNE
}
// pack two floats -> bf16x2 (round-half-up; operands are p in [0,~64], safe)
static __device__ __forceinline__ unsigned pk2bf(float lo, float hi) {
    union { float f; unsigned u; } a, b; a.f = lo; b.f = hi;
    return __builtin_amdgcn_perm(b.u + 0x8000u, a.u + 0x8000u, 0x07060302u);
}
static __device__ __forceinline__ void gload_lds16(const unsigned short* g, unsigned short* l) {
    __builtin_amdgcn_global_load_lds(
        (__attribute__((address_space(1))) void*)g,
        (__attribute__((address_space(3))) void*)l, 16, 0, 0);
}

#define SCQ 0.180336880f   // log2(e)/8, folded into Q projection

// ---------------------------------------------------------------------------
// All fp32->bf16 casts in one launch: blocks [0,4096) = x, then 4x512 = weights
// ---------------------------------------------------------------------------
__global__ void cast_all(const float* __restrict__ x,
                         const float* __restrict__ w0, const float* __restrict__ w1,
                         const float* __restrict__ w2, const float* __restrict__ w3,
                         unsigned short* __restrict__ xb,
                         unsigned short* __restrict__ wb)
{
    const int bid = blockIdx.x;
    const float* src;
    unsigned short* dst;
    int i;
    if (bid < 4096) {
        src = x; dst = xb; i = (bid * 256 + threadIdx.x) * 8;
    } else {
        const int wz = (bid - 4096) >> 9;
        const float* ws[4] = {w0, w1, w2, w3};
        src = ws[wz];
        dst = wb + (size_t)wz * (EMBED * EMBED);
        i = (((bid - 4096) & 511) * 256 + threadIdx.x) * 8;
    }
    float4 a = *(const float4*)(src + i);
    float4 b = *(const float4*)(src + i + 4);
    union { int4 v; unsigned short u[8]; } pk;
    pk.u[0] = f2bf(a.x); pk.u[1] = f2bf(a.y); pk.u[2] = f2bf(a.z); pk.u[3] = f2bf(a.w);
    pk.u[4] = f2bf(b.x); pk.u[5] = f2bf(b.y); pk.u[6] = f2bf(b.z); pk.u[7] = f2bf(b.w);
    *(int4*)(dst + i) = pk.v;
}

// ---------------------------------------------------------------------------
// Fused QKV GEMM (m97 staging, proven): X staged ONCE per k-step, 3 weight
// tiles staged alongside -> 48 MFMA per 8 gloads. Outputs:
//   z0: Q row-major, pre-scaled by SCQ.  z1: K row-major.
//   z2: V transposed into VtG[bh][d][s] (no masking -- mask folded into attn).
// XCD swizzle: linear dispatch id = by*8+bx -> XCD = bx; give each XCD a
// contiguous 1024-token slice (2 MB, L2-resident) across all feature blocks.
// ---------------------------------------------------------------------------
__global__ __launch_bounds__(256, 2)
void gemm_qkv(const unsigned short* __restrict__ Xb,
              const unsigned short* __restrict__ Wall,
              const float* __restrict__ bq, const float* __restrict__ bk,
              const float* __restrict__ bv,
              unsigned short* __restrict__ Qw, unsigned short* __restrict__ Kw,
              unsigned short* __restrict__ VtG)
{
    __shared__ unsigned short Ws[3][128][32];
    __shared__ unsigned short Xs[128][32];

    const int tid  = threadIdx.x;
    const int bx   = blockIdx.x, by = blockIdx.y;
    const int f0   = (by >> 3) * 128;                  // feature block 0..7
    const int t0   = ((bx << 3) | (by & 7)) * 128;     // token block: XCD-local
    const int lane = tid & 63, m = lane & 15, quad = lane >> 4;
    const int wid  = tid >> 6;
    const int wf   = (wid & 1) * 64;
    const int wt   = (wid >> 1) * 64;

    const int r    = tid >> 2, cc = tid & 3, sw = (tid >> 4) & 3;
    const int gcol = (cc ^ sw) << 3;
    const unsigned short* Xp = Xb + (size_t)(t0 + r) * EMBED + gcol;
    const unsigned short* Wp = Wall + (size_t)(f0 + r) * EMBED + gcol;
    unsigned short* XsL = &Xs[0][0] + tid * 8;
    unsigned short* WsL = &Ws[0][0][0] + tid * 8;

    const int qs = (quad ^ ((m >> 2) & 3)) << 3;

    f32x4 aq[4][4] = {}, ak[4][4] = {}, av[4][4] = {};

    for (int k0 = 0; k0 < EMBED; k0 += 32) {
        __syncthreads();
        gload_lds16(Xp + k0,              XsL);
        gload_lds16(Xp + k0 + 64 * EMBED, XsL + 2048);
#pragma unroll
        for (int z = 0; z < 3; ++z) {
            const unsigned short* wz = Wp + (size_t)z * EMBED * EMBED + k0;
            gload_lds16(wz,              WsL + z * 4096);
            gload_lds16(wz + 64 * EMBED, WsL + z * 4096 + 2048);
        }
        __syncthreads();

        short8 bf4[4];
#pragma unroll
        for (int nb = 0; nb < 4; ++nb)
            bf4[nb] = *(const short8*)&Xs[wt + nb * 16 + m][qs];

#pragma unroll
        for (int z = 0; z < 3; ++z) {
            short8 af[4];
#pragma unroll
            for (int mb = 0; mb < 4; ++mb)
                af[mb] = *(const short8*)&Ws[z][wf + mb * 16 + m][qs];
            f32x4 (&acc)[4][4] = (z == 0) ? aq : (z == 1) ? ak : av;
#pragma unroll
            for (int mb = 0; mb < 4; ++mb)
#pragma unroll
                for (int nb = 0; nb < 4; ++nb)
                    acc[mb][nb] = __builtin_amdgcn_mfma_f32_16x16x32_bf16(
                        af[mb], bf4[nb], acc[mb][nb], 0, 0, 0);
        }
    }

    // ---- Q epilogue (scaled by SCQ) ----
#pragma unroll
    for (int mb = 0; mb < 4; ++mb) {
        const int feat = f0 + wf + mb * 16 + quad * 4;
        float4 bv4 = *(const float4*)&bq[feat];
#pragma unroll
        for (int nb = 0; nb < 4; ++nb) {
            const int tok = t0 + wt + nb * 16 + m;
            ushort4 pk;
            pk.x = f2bf((aq[mb][nb][0] + bv4.x) * SCQ);
            pk.y = f2bf((aq[mb][nb][1] + bv4.y) * SCQ);
            pk.z = f2bf((aq[mb][nb][2] + bv4.z) * SCQ);
            pk.w = f2bf((aq[mb][nb][3] + bv4.w) * SCQ);
            *(ushort4*)(Qw + (size_t)tok * EMBED + feat) = pk;
        }
    }
    // ---- K epilogue ----
#pragma unroll
    for (int mb = 0; mb < 4; ++mb) {
        const int feat = f0 + wf + mb * 16 + quad * 4;
        float4 bv4 = *(const float4*)&bk[feat];
#pragma unroll
        for (int nb = 0; nb < 4; ++nb) {
            const int tok = t0 + wt + nb * 16 + m;
            ushort4 pk;
            pk.x = f2bf(ak[mb][nb][0] + bv4.x);
            pk.y = f2bf(ak[mb][nb][1] + bv4.y);
            pk.z = f2bf(ak[mb][nb][2] + bv4.z);
            pk.w = f2bf(ak[mb][nb][3] + bv4.w);
            *(ushort4*)(Kw + (size_t)tok * EMBED + feat) = pk;
        }
    }
    // ---- V epilogue: transposed, unmasked ----
    {
        const int h = (f0 + wf) >> 6;              // feat block is h-aligned (64)
#pragma unroll
        for (int nb = 0; nb < 4; ++nb) {
            const int tok = t0 + wt + nb * 16 + m;
            const int b   = tok >> 11;
            const int s   = tok & (SEQ - 1);
            const size_t base = ((size_t)(b * HEADS + h) * HDIM) * SEQ + s;
#pragma unroll
            for (int mb = 0; mb < 4; ++mb) {
                const int feat  = f0 + wf + mb * 16 + quad * 4;
                const int dbase = mb * 16 + quad * 4;
                float4 bv4 = *(const float4*)&bv[feat];
                VtG[base + (size_t)(dbase + 0) * SEQ] = f2bf(av[mb][nb][0] + bv4.x);
                VtG[base + (size_t)(dbase + 1) * SEQ] = f2bf(av[mb][nb][1] + bv4.y);
                VtG[base + (size_t)(dbase + 2) * SEQ] = f2bf(av[mb][nb][2] + bv4.z);
                VtG[base + (size_t)(dbase + 3) * SEQ] = f2bf(av[mb][nb][3] + bv4.w);
            }
        }
    }
}

// ---------------------------------------------------------------------------
// MFMA flash attention, 32x32x16.
//  - Mask folded into scores: 5th K-step MFMA with A[key][0]=maskbit(key),
//    B[q][0]=bf16(-1024) -> masked s -= 1024 exactly -> p = exp2(s) == 0.
//    Denominator lr = f32 sum of p (16 adds/kb) + one shfl_xor(32) at end.
//    (replaces the o2 mask-row accumulator: -4 MFMA/kt, -4KB LDS reads/kt,
//     -16 VGPR, no V zeroing, no VROWS=72 layout, no maskrow kernel)
//  - Double-buffered K/V LDS + register prefetch of kt+64 issued before the
//    compute phase: one barrier per kt-iter, HBM/L2 latency hidden under MFMA.
//  - XCD swizzle: 16 qb-blocks of each (b,h) share K/V -> keep them on one
//    XCD (grid 1024 = 8*128 exactly; bijective).
// ---------------------------------------------------------------------------
__global__ __launch_bounds__(256, 4)
void attn_mfma(const unsigned short* __restrict__ Qb,
               const unsigned short* __restrict__ Kb,
               const unsigned short* __restrict__ VtG,
               const int* __restrict__ mask,
               unsigned short* __restrict__ Ob)
{
    __shared__ unsigned short Ks[2][64][72];  // [buf][key][d]
    __shared__ unsigned short Vs[2][64][72];  // [buf][d][key]

    const int tid  = threadIdx.x;
    // XCD-local remap: XCD = blockIdx.x % 8 gets 8 contiguous (b,h) groups
    const int lin  = (blockIdx.x & 7) * 128 + (blockIdx.x >> 3);
    const int qb   = lin & 15;
    const int h    = (lin >> 4) & 15;
    const int b    = lin >> 8;
    const int wid  = tid >> 6, lane = tid & 63;
    const int q32  = lane & 31, hi = lane >> 5;
    const int tb   = b * SEQ;
    const int q    = qb * 128 + wid * 32 + q32;

    // Q B-frags (pre-scaled): k = st*16 + hi*8 + j
    const unsigned short* qrow = Qb + (size_t)(tb + q) * EMBED + h * HDIM;
    short8 qf[4];
#pragma unroll
    for (int st = 0; st < 4; ++st)
        qf[st] = *(const short8*)(qrow + st * 16 + hi * 8);

    // mask B-frag: B[q][k]: nonzero only at k==0 (lanes hi==0, j==0)
    short8 mqf = {0, 0, 0, 0, 0, 0, 0, 0};
    mqf[0] = hi ? (short)0 : (short)0xC480;   // bf16(-1024), exact

    f32x16 o0, o1, z16;
#pragma unroll
    for (int i = 0; i < 16; ++i) { z16[i] = 0.f; }
    o0 = z16; o1 = z16;
    float lr = 0.f;

    // staging: thread -> (row = tid>>2, 16-elem col group = (tid&3)*16)
    const int sr = tid >> 2, sc = (tid & 3) * 16;
    const unsigned short* kSrc = Kb + (size_t)(tb + sr) * EMBED + h * HDIM + sc;
    const unsigned short* vSrc = VtG + ((size_t)(b * HEADS + h) * HDIM + sr) * SEQ + sc;
    const int* mrow = mask + b * SEQ;

    // prologue: prefetch kt = 0
    int4 kv0 = *(const int4*)(kSrc);
    int4 kv1 = *(const int4*)(kSrc + 8);
    int4 vv0 = *(const int4*)(vSrc);
    int4 vv1 = *(const int4*)(vSrc + 8);
    int mva = mrow[q32];
    int mvb = mrow[32 + q32];

    int cur = 0;
    for (int kt = 0; kt < SEQ; kt += 64, cur ^= 1) {
        // write buf[cur]; all waves passed the previous barrier, so readers of
        // buf[cur] (iteration kt-128) are done.
        *(int4*)&Ks[cur][sr][sc]     = kv0;
        *(int4*)&Ks[cur][sr][sc + 8] = kv1;
        *(int4*)&Vs[cur][sr][sc]     = vv0;
        *(int4*)&Vs[cur][sr][sc + 8] = vv1;
        __syncthreads();

        // mask A-frags for THIS tile (before prefetch overwrites mva/mvb):
        // A[key][k]: nonzero only at k==0: maskbit = 1.0 if key masked
        short8 mkfa = {0, 0, 0, 0, 0, 0, 0, 0};
        short8 mkfb = {0, 0, 0, 0, 0, 0, 0, 0};
        mkfa[0] = (hi == 0 && mva == 0) ? (short)0x3F80 : (short)0;
        mkfb[0] = (hi == 0 && mvb == 0) ? (short)0x3F80 : (short)0;

        // prefetch kt+64 into regs: latency hides under the MFMA phase below
        const int ktn = kt + 64;
        if (ktn < SEQ) {
            kv0 = *(const int4*)(kSrc + (size_t)ktn * EMBED);
            kv1 = *(const int4*)(kSrc + (size_t)ktn * EMBED + 8);
            vv0 = *(const int4*)(vSrc + ktn);
            vv1 = *(const int4*)(vSrc + ktn + 8);
            mva = mrow[ktn + q32];
            mvb = mrow[ktn + 32 + q32];
        }

#pragma unroll
        for (int kb = 0; kb < 2; ++kb) {
            // S' = mask-bias + K·Q^T over 4 d-steps (Q pre-scaled -> exp2 domain)
            f32x16 s = __builtin_amdgcn_mfma_f32_32x32x16_bf16(
                kb ? mkfb : mkfa, mqf, z16, 0, 0, 0);
#pragma unroll
            for (int st = 0; st < 4; ++st) {
                short8 kf = *(const short8*)&Ks[cur][kb * 32 + q32][st * 16 + hi * 8];
                s = __builtin_amdgcn_mfma_f32_32x32x16_bf16(kf, qf[st], s, 0, 0, 0);
            }

            // p = exp2(s); masked keys give exactly 0
            float p[16];
#pragma unroll
            for (int i = 0; i < 16; ++i) p[i] = __builtin_amdgcn_exp2f(s[i]);

            // denominator: f32 tree-sum of this lane's 16 p values
            lr += (((p[0] + p[1]) + (p[2] + p[3])) + ((p[4] + p[5]) + (p[6] + p[7])))
                + (((p[8] + p[9]) + (p[10] + p[11])) + ((p[12] + p[13]) + (p[14] + p[15])));

            unsigned D[8];
#pragma unroll
            for (int j = 0; j < 8; ++j) D[j] = pk2bf(p[2 * j], p[2 * j + 1]);

            // PV over 2 chunks of 16 keys; B-frag via partner exchange (R6-proven)
#pragma unroll
            for (int cl = 0; cl < 2; ++cl) {
                unsigned s0 = hi ? D[4 * cl + 0] : D[4 * cl + 2];
                unsigned s1 = hi ? D[4 * cl + 1] : D[4 * cl + 3];
                unsigned r0 = (unsigned)__shfl_xor((int)s0, 32);
                unsigned r1 = (unsigned)__shfl_xor((int)s1, 32);
                union { uint4 u; short8 s8; } fr;
                fr.u.x = hi ? r0 : D[4 * cl + 0];
                fr.u.y = hi ? r1 : D[4 * cl + 1];
                fr.u.z = hi ? D[4 * cl + 2] : r0;
                fr.u.w = hi ? D[4 * cl + 3] : r1;

                const int kcol = kb * 32 + cl * 16 + hi * 8;
                short8 vf0 = *(const short8*)&Vs[cur][q32][kcol];
                short8 vf1 = *(const short8*)&Vs[cur][32 + q32][kcol];
                o0 = __builtin_amdgcn_mfma_f32_32x32x16_bf16(vf0, fr.s8, o0, 0, 0, 0);
                o1 = __builtin_amdgcn_mfma_f32_32x32x16_bf16(vf1, fr.s8, o1, 0, 0, 0);
            }
        }
    }

    // lr held half per hi-lane pair: combine, then normalize
    const float lrt = lr + __shfl_xor(lr, 32);
    const float inv = 1.0f / lrt;
    unsigned short* orow = Ob + (size_t)(tb + q) * EMBED + h * HDIM;
#pragma unroll
    for (int db = 0; db < 2; ++db) {
        const f32x16& oo = db ? o1 : o0;
#pragma unroll
        for (int qg = 0; qg < 4; ++qg) {
            ushort4 pk;
            pk.x = f2bf(oo[qg * 4 + 0] * inv);
            pk.y = f2bf(oo[qg * 4 + 1] * inv);
            pk.z = f2bf(oo[qg * 4 + 2] * inv);
            pk.w = f2bf(oo[qg * 4 + 3] * inv);
            *(ushort4*)(orow + db * 32 + qg * 8 + hi * 4) = pk;
        }
    }
}

// ---------------------------------------------------------------------------
// Output GEMM (m97 staging, proven): fp32 out. Same XCD-local token swizzle.
// ---------------------------------------------------------------------------
__global__ __launch_bounds__(256, 2)
void gemm_o(const unsigned short* __restrict__ W, const unsigned short* __restrict__ X,
            const float* __restrict__ bias, float* __restrict__ Cout)
{
    __shared__ unsigned short Ws[128][32];
    __shared__ unsigned short Xs[128][32];

    const int tid  = threadIdx.x;
    const int bx   = blockIdx.x, by = blockIdx.y;
    const int f0   = (by >> 3) * 128;
    const int t0   = ((bx << 3) | (by & 7)) * 128;
    const int lane = tid & 63, m = lane & 15, quad = lane >> 4;
    const int wid  = tid >> 6;
    const int wf   = (wid & 1) * 64;
    const int wt   = (wid >> 1) * 64;

    const int r    = tid >> 2, cc = tid & 3, sw = (tid >> 4) & 3;
    const int gcol = (cc ^ sw) << 3;
    const unsigned short* Wp = W + (size_t)(f0 + r) * EMBED + gcol;
    const unsigned short* Xp = X + (size_t)(t0 + r) * EMBED + gcol;
    unsigned short* WsL = &Ws[0][0] + tid * 8;
    unsigned short* XsL = &Xs[0][0] + tid * 8;

    const int qs = (quad ^ ((m >> 2) & 3)) << 3;

    f32x4 acc[4][4] = {};

    for (int k0 = 0; k0 < EMBED; k0 += 32) {
        __syncthreads();
        gload_lds16(Wp + k0,              WsL);
        gload_lds16(Wp + k0 + 64 * EMBED, WsL + 2048);
        gload_lds16(Xp + k0,              XsL);
        gload_lds16(Xp + k0 + 64 * EMBED, XsL + 2048);
        __syncthreads();

        short8 af[4], bf4[4];
#pragma unroll
        for (int mb = 0; mb < 4; ++mb)
            af[mb] = *(const short8*)&Ws[wf + mb * 16 + m][qs];
#pragma unroll
        for (int nb = 0; nb < 4; ++nb)
            bf4[nb] = *(const short8*)&Xs[wt + nb * 16 + m][qs];
#pragma unroll
        for (int mb = 0; mb < 4; ++mb)
#pragma unroll
            for (int nb = 0; nb < 4; ++nb)
                acc[mb][nb] = __builtin_amdgcn_mfma_f32_16x16x32_bf16(
                    af[mb], bf4[nb], acc[mb][nb], 0, 0, 0);
    }

#pragma unroll
    for (int mb = 0; mb < 4; ++mb) {
        const int feat = f0 + wf + mb * 16 + quad * 4;
        float4 bv4 = *(const float4*)&bias[feat];
#pragma unroll
        for (int nb = 0; nb < 4; ++nb) {
            const int tok = t0 + wt + nb * 16 + m;
            float4 st;
            st.x = acc[mb][nb][0] + bv4.x;
            st.y = acc[mb][nb][1] + bv4.y;
            st.z = acc[mb][nb][2] + bv4.z;
            st.w = acc[mb][nb][3] + bv4.w;
            *(float4*)(Cout + (size_t)tok * EMBED + feat) = st;
        }
    }
}

// ---------------------------------------------------------------------------
extern "C" void kernel_launch(void* const* d_in, const int* in_sizes, int n_in,
                              void* d_out, int out_size, void* d_ws, size_t ws_size,
                              hipStream_t stream)
{
    const float* x    = (const float*)d_in[0];
    const int*   mask = (const int*)  d_in[1];
    const float* Wq   = (const float*)d_in[2];
    const float* bq   = (const float*)d_in[3];
    const float* Wk   = (const float*)d_in[4];
    const float* bk   = (const float*)d_in[5];
    const float* Wv   = (const float*)d_in[6];
    const float* bv   = (const float*)d_in[7];
    const float* Wo   = (const float*)d_in[8];
    const float* bo   = (const float*)d_in[9];
    float* out = (float*)d_out;

    const size_t NE = (size_t)NTOK * EMBED;
    const size_t WE = (size_t)EMBED * EMBED;
    unsigned short* Xb  = (unsigned short*)d_ws;
    unsigned short* Wqb = Xb + NE;            // Wq,Wk,Wv,Wo contiguous
    unsigned short* Wob = Wqb + 3 * WE;
    unsigned short* Qw  = Wob + WE;
    unsigned short* Kw  = Qw + NE;
    unsigned short* VtG = Kw + NE;            // [b*H+h][d][s], d = 0..63
    unsigned short* Ow  = Xb;                 // reuse: Xb dead after projections

    cast_all<<<4096 + 2048, 256, 0, stream>>>(x, Wq, Wk, Wv, Wo, Xb, Wqb);

    gemm_qkv<<<dim3(8, 64), 256, 0, stream>>>(Xb, Wqb, bq, bk, bv, Qw, Kw, VtG);

    attn_mfma<<<BATCH * HEADS * (SEQ / 128), 256, 0, stream>>>(Qw, Kw, VtG, mask, Ow);

    gemm_o<<<dim3(8, 64), 256, 0, stream>>>(Wob, Ow, bo, out);
}

// Round 2
// 277.211 us; speedup vs baseline: 1.1226x; 1.1226x over previous
//
#include <hip/hip_runtime.h>

#define BATCH 4
#define SEQ   2048
#define EMBED 1024
#define HEADS 16
#define HDIM  64
#define NTOK  (BATCH*SEQ)

typedef __attribute__((ext_vector_type(8)))  short short8;   // 8 bf16 = MFMA A/B frag
typedef __attribute__((ext_vector_type(4)))  float f32x4;    // 16x16 C frag
typedef __attribute__((ext_vector_type(16))) float f32x16;   // 32x32 C frag

static __device__ __forceinline__ unsigned short f2bf(float f) {
    union { float f; unsigned u; } v; v.f = f;
    return (unsigned short)((v.u + 0x7FFFu + ((v.u >> 16) & 1u)) >> 16);  // RNE
}
// pack two floats -> bf16x2 (round-half-up; operands are p in [0,~64], safe)
static __device__ __forceinline__ unsigned pk2bf(float lo, float hi) {
    union { float f; unsigned u; } a, b; a.f = lo; b.f = hi;
    return __builtin_amdgcn_perm(b.u + 0x8000u, a.u + 0x8000u, 0x07060302u);
}
static __device__ __forceinline__ void gload_lds16(const unsigned short* g, unsigned short* l) {
    __builtin_amdgcn_global_load_lds(
        (__attribute__((address_space(1))) void*)g,
        (__attribute__((address_space(3))) void*)l, 16, 0, 0);
}

#define SCQ 0.180336880f   // log2(e)/8, folded into Q projection

// ---------------------------------------------------------------------------
// All fp32->bf16 casts in one launch: blocks [0,4096) = x, then 4x512 = weights
// ---------------------------------------------------------------------------
__global__ void cast_all(const float* __restrict__ x,
                         const float* __restrict__ w0, const float* __restrict__ w1,
                         const float* __restrict__ w2, const float* __restrict__ w3,
                         unsigned short* __restrict__ xb,
                         unsigned short* __restrict__ wb)
{
    const int bid = blockIdx.x;
    const float* src;
    unsigned short* dst;
    int i;
    if (bid < 4096) {
        src = x; dst = xb; i = (bid * 256 + threadIdx.x) * 8;
    } else {
        const int wz = (bid - 4096) >> 9;
        const float* ws[4] = {w0, w1, w2, w3};
        src = ws[wz];
        dst = wb + (size_t)wz * (EMBED * EMBED);
        i = (((bid - 4096) & 511) * 256 + threadIdx.x) * 8;
    }
    float4 a = *(const float4*)(src + i);
    float4 b = *(const float4*)(src + i + 4);
    union { int4 v; unsigned short u[8]; } pk;
    pk.u[0] = f2bf(a.x); pk.u[1] = f2bf(a.y); pk.u[2] = f2bf(a.z); pk.u[3] = f2bf(a.w);
    pk.u[4] = f2bf(b.x); pk.u[5] = f2bf(b.y); pk.u[6] = f2bf(b.z); pk.u[7] = f2bf(b.w);
    *(int4*)(dst + i) = pk.v;
}

// ---------------------------------------------------------------------------
// Fused QKV GEMM (m97 staging, proven): X staged ONCE per k-step, 3 weight
// tiles staged alongside -> 48 MFMA per 8 gloads. Outputs:
//   z0: Q row-major, pre-scaled by SCQ.  z1: K row-major.
//   z2: V transposed into VtG[bh][d][s] (no masking -- mask folded into attn).
// XCD swizzle: linear dispatch id = by*8+bx -> XCD = bx; give each XCD a
// contiguous 1024-token slice (2 MB, L2-resident) across all feature blocks.
// ---------------------------------------------------------------------------
__global__ __launch_bounds__(256, 2)
void gemm_qkv(const unsigned short* __restrict__ Xb,
              const unsigned short* __restrict__ Wall,
              const float* __restrict__ bq, const float* __restrict__ bk,
              const float* __restrict__ bv,
              unsigned short* __restrict__ Qw, unsigned short* __restrict__ Kw,
              unsigned short* __restrict__ VtG)
{
    __shared__ unsigned short Ws[3][128][32];
    __shared__ unsigned short Xs[128][32];

    const int tid  = threadIdx.x;
    const int bx   = blockIdx.x, by = blockIdx.y;
    const int f0   = (by >> 3) * 128;                  // feature block 0..7
    const int t0   = ((bx << 3) | (by & 7)) * 128;     // token block: XCD-local
    const int lane = tid & 63, m = lane & 15, quad = lane >> 4;
    const int wid  = tid >> 6;
    const int wf   = (wid & 1) * 64;
    const int wt   = (wid >> 1) * 64;

    const int r    = tid >> 2, cc = tid & 3, sw = (tid >> 4) & 3;
    const int gcol = (cc ^ sw) << 3;
    const unsigned short* Xp = Xb + (size_t)(t0 + r) * EMBED + gcol;
    const unsigned short* Wp = Wall + (size_t)(f0 + r) * EMBED + gcol;
    unsigned short* XsL = &Xs[0][0] + tid * 8;
    unsigned short* WsL = &Ws[0][0][0] + tid * 8;

    const int qs = (quad ^ ((m >> 2) & 3)) << 3;

    f32x4 aq[4][4] = {}, ak[4][4] = {}, av[4][4] = {};

    for (int k0 = 0; k0 < EMBED; k0 += 32) {
        __syncthreads();
        gload_lds16(Xp + k0,              XsL);
        gload_lds16(Xp + k0 + 64 * EMBED, XsL + 2048);
#pragma unroll
        for (int z = 0; z < 3; ++z) {
            const unsigned short* wz = Wp + (size_t)z * EMBED * EMBED + k0;
            gload_lds16(wz,              WsL + z * 4096);
            gload_lds16(wz + 64 * EMBED, WsL + z * 4096 + 2048);
        }
        __syncthreads();

        short8 bf4[4];
#pragma unroll
        for (int nb = 0; nb < 4; ++nb)
            bf4[nb] = *(const short8*)&Xs[wt + nb * 16 + m][qs];

#pragma unroll
        for (int z = 0; z < 3; ++z) {
            short8 af[4];
#pragma unroll
            for (int mb = 0; mb < 4; ++mb)
                af[mb] = *(const short8*)&Ws[z][wf + mb * 16 + m][qs];
            f32x4 (&acc)[4][4] = (z == 0) ? aq : (z == 1) ? ak : av;
#pragma unroll
            for (int mb = 0; mb < 4; ++mb)
#pragma unroll
                for (int nb = 0; nb < 4; ++nb)
                    acc[mb][nb] = __builtin_amdgcn_mfma_f32_16x16x32_bf16(
                        af[mb], bf4[nb], acc[mb][nb], 0, 0, 0);
        }
    }

    // ---- Q epilogue (scaled by SCQ) ----
#pragma unroll
    for (int mb = 0; mb < 4; ++mb) {
        const int feat = f0 + wf + mb * 16 + quad * 4;
        float4 bv4 = *(const float4*)&bq[feat];
#pragma unroll
        for (int nb = 0; nb < 4; ++nb) {
            const int tok = t0 + wt + nb * 16 + m;
            ushort4 pk;
            pk.x = f2bf((aq[mb][nb][0] + bv4.x) * SCQ);
            pk.y = f2bf((aq[mb][nb][1] + bv4.y) * SCQ);
            pk.z = f2bf((aq[mb][nb][2] + bv4.z) * SCQ);
            pk.w = f2bf((aq[mb][nb][3] + bv4.w) * SCQ);
            *(ushort4*)(Qw + (size_t)tok * EMBED + feat) = pk;
        }
    }
    // ---- K epilogue ----
#pragma unroll
    for (int mb = 0; mb < 4; ++mb) {
        const int feat = f0 + wf + mb * 16 + quad * 4;
        float4 bv4 = *(const float4*)&bk[feat];
#pragma unroll
        for (int nb = 0; nb < 4; ++nb) {
            const int tok = t0 + wt + nb * 16 + m;
            ushort4 pk;
            pk.x = f2bf(ak[mb][nb][0] + bv4.x);
            pk.y = f2bf(ak[mb][nb][1] + bv4.y);
            pk.z = f2bf(ak[mb][nb][2] + bv4.z);
            pk.w = f2bf(ak[mb][nb][3] + bv4.w);
            *(ushort4*)(Kw + (size_t)tok * EMBED + feat) = pk;
        }
    }
    // ---- V epilogue: transposed, unmasked ----
    {
        const int h = (f0 + wf) >> 6;              // feat block is h-aligned (64)
#pragma unroll
        for (int nb = 0; nb < 4; ++nb) {
            const int tok = t0 + wt + nb * 16 + m;
            const int b   = tok >> 11;
            const int s   = tok & (SEQ - 1);
            const size_t base = ((size_t)(b * HEADS + h) * HDIM) * SEQ + s;
#pragma unroll
            for (int mb = 0; mb < 4; ++mb) {
                const int feat  = f0 + wf + mb * 16 + quad * 4;
                const int dbase = mb * 16 + quad * 4;
                float4 bv4 = *(const float4*)&bv[feat];
                VtG[base + (size_t)(dbase + 0) * SEQ] = f2bf(av[mb][nb][0] + bv4.x);
                VtG[base + (size_t)(dbase + 1) * SEQ] = f2bf(av[mb][nb][1] + bv4.y);
                VtG[base + (size_t)(dbase + 2) * SEQ] = f2bf(av[mb][nb][2] + bv4.z);
                VtG[base + (size_t)(dbase + 3) * SEQ] = f2bf(av[mb][nb][3] + bv4.w);
            }
        }
    }
}

// ---------------------------------------------------------------------------
// MFMA flash attention, 32x32x16. PROVEN two-barrier single-buffer schedule
// (R0 structure; R1's single-barrier double-buffer regressed 95->145us:
// barrier-drained prefetch stalled all waves, and 37KB LDS capped residency).
//  - Mask folded into scores (R1-proven): seed MFMA with A[key][0]=maskbit,
//    B[q][0]=bf16(-1024) -> masked s -= 1024 -> p = exp2(s) == 0 exactly.
//    Denominator = f32 sum of p + one shfl_xor(32). No o2 accumulator, no
//    mask rows in LDS: tile is 18KB (vs 23KB R0) -> ~5 blocks/CU resident.
//  - XCD swizzle (R1-proven: FETCH 147->32MB): 16 qb-blocks of one (b,h)
//    pinned to one XCD.
// ---------------------------------------------------------------------------
__global__ __launch_bounds__(256, 4)
void attn_mfma(const unsigned short* __restrict__ Qb,
               const unsigned short* __restrict__ Kb,
               const unsigned short* __restrict__ VtG,
               const int* __restrict__ mask,
               unsigned short* __restrict__ Ob)
{
    __shared__ unsigned short Ks[64][72];     // [key][d]
    __shared__ unsigned short Vs[64][72];     // [d][key]

    const int tid  = threadIdx.x;
    // XCD-local remap: XCD = blockIdx.x % 8 gets 8 contiguous (b,h) groups
    const int lin  = (blockIdx.x & 7) * 128 + (blockIdx.x >> 3);
    const int qb   = lin & 15;
    const int h    = (lin >> 4) & 15;
    const int b    = lin >> 8;
    const int wid  = tid >> 6, lane = tid & 63;
    const int q32  = lane & 31, hi = lane >> 5;
    const int tb   = b * SEQ;
    const int q    = qb * 128 + wid * 32 + q32;

    // Q B-frags (pre-scaled): k = st*16 + hi*8 + j
    const unsigned short* qrow = Qb + (size_t)(tb + q) * EMBED + h * HDIM;
    short8 qf[4];
#pragma unroll
    for (int st = 0; st < 4; ++st)
        qf[st] = *(const short8*)(qrow + st * 16 + hi * 8);

    // mask B-frag: B[q][k]: nonzero only at k==0 (lanes hi==0, j==0)
    short8 mqf = {0, 0, 0, 0, 0, 0, 0, 0};
    mqf[0] = hi ? (short)0 : (short)0xC480;   // bf16(-1024), exact

    f32x16 o0, o1, z16;
#pragma unroll
    for (int i = 0; i < 16; ++i) { z16[i] = 0.f; }
    o0 = z16; o1 = z16;
    float lr = 0.f;

    // staging: thread -> (row = tid>>2, 16-elem col group = (tid&3)*16)
    const int sr = tid >> 2, sc = (tid & 3) * 16;
    const unsigned short* kSrc = Kb + (size_t)(tb + sr) * EMBED + h * HDIM + sc;
    const unsigned short* vSrc = VtG + ((size_t)(b * HEADS + h) * HDIM + sr) * SEQ + sc;
    const int* mrow = mask + b * SEQ;

    for (int kt = 0; kt < SEQ; kt += 64) {
        // loads for THIS tile at loop top; cross-block TLP hides the latency
        int4 kv0 = *(const int4*)(kSrc + (size_t)kt * EMBED);
        int4 kv1 = *(const int4*)(kSrc + (size_t)kt * EMBED + 8);
        int4 vv0 = *(const int4*)(vSrc + kt);
        int4 vv1 = *(const int4*)(vSrc + kt + 8);
        const int mva = mrow[kt + q32];
        const int mvb = mrow[kt + 32 + q32];
        __syncthreads();
        *(int4*)&Ks[sr][sc]     = kv0;
        *(int4*)&Ks[sr][sc + 8] = kv1;
        *(int4*)&Vs[sr][sc]     = vv0;
        *(int4*)&Vs[sr][sc + 8] = vv1;
        __syncthreads();

        // mask A-frags: A[key][k]: nonzero only at k==0: maskbit = 1.0 if masked
        short8 mkfa = {0, 0, 0, 0, 0, 0, 0, 0};
        short8 mkfb = {0, 0, 0, 0, 0, 0, 0, 0};
        mkfa[0] = (hi == 0 && mva == 0) ? (short)0x3F80 : (short)0;
        mkfb[0] = (hi == 0 && mvb == 0) ? (short)0x3F80 : (short)0;

#pragma unroll
        for (int kb = 0; kb < 2; ++kb) {
            // S' = mask-bias + K·Q^T over 4 d-steps (Q pre-scaled -> exp2 domain)
            f32x16 s = __builtin_amdgcn_mfma_f32_32x32x16_bf16(
                kb ? mkfb : mkfa, mqf, z16, 0, 0, 0);
#pragma unroll
            for (int st = 0; st < 4; ++st) {
                short8 kf = *(const short8*)&Ks[kb * 32 + q32][st * 16 + hi * 8];
                s = __builtin_amdgcn_mfma_f32_32x32x16_bf16(kf, qf[st], s, 0, 0, 0);
            }

            // p = exp2(s); masked keys give exactly 0
            float p[16];
#pragma unroll
            for (int i = 0; i < 16; ++i) p[i] = __builtin_amdgcn_exp2f(s[i]);

            // denominator: f32 tree-sum of this lane's 16 p values
            lr += (((p[0] + p[1]) + (p[2] + p[3])) + ((p[4] + p[5]) + (p[6] + p[7])))
                + (((p[8] + p[9]) + (p[10] + p[11])) + ((p[12] + p[13]) + (p[14] + p[15])));

            unsigned D[8];
#pragma unroll
            for (int j = 0; j < 8; ++j) D[j] = pk2bf(p[2 * j], p[2 * j + 1]);

            // PV over 2 chunks of 16 keys; B-frag via partner exchange (R6-proven)
#pragma unroll
            for (int cl = 0; cl < 2; ++cl) {
                unsigned s0 = hi ? D[4 * cl + 0] : D[4 * cl + 2];
                unsigned s1 = hi ? D[4 * cl + 1] : D[4 * cl + 3];
                unsigned r0 = (unsigned)__shfl_xor((int)s0, 32);
                unsigned r1 = (unsigned)__shfl_xor((int)s1, 32);
                union { uint4 u; short8 s8; } fr;
                fr.u.x = hi ? r0 : D[4 * cl + 0];
                fr.u.y = hi ? r1 : D[4 * cl + 1];
                fr.u.z = hi ? D[4 * cl + 2] : r0;
                fr.u.w = hi ? D[4 * cl + 3] : r1;

                const int kcol = kb * 32 + cl * 16 + hi * 8;
                short8 vf0 = *(const short8*)&Vs[q32][kcol];
                short8 vf1 = *(const short8*)&Vs[32 + q32][kcol];
                o0 = __builtin_amdgcn_mfma_f32_32x32x16_bf16(vf0, fr.s8, o0, 0, 0, 0);
                o1 = __builtin_amdgcn_mfma_f32_32x32x16_bf16(vf1, fr.s8, o1, 0, 0, 0);
            }
        }
    }

    // lr held half per hi-lane pair: combine, then normalize
    const float lrt = lr + __shfl_xor(lr, 32);
    const float inv = 1.0f / lrt;
    unsigned short* orow = Ob + (size_t)(tb + q) * EMBED + h * HDIM;
#pragma unroll
    for (int db = 0; db < 2; ++db) {
        const f32x16& oo = db ? o1 : o0;
#pragma unroll
        for (int qg = 0; qg < 4; ++qg) {
            ushort4 pk;
            pk.x = f2bf(oo[qg * 4 + 0] * inv);
            pk.y = f2bf(oo[qg * 4 + 1] * inv);
            pk.z = f2bf(oo[qg * 4 + 2] * inv);
            pk.w = f2bf(oo[qg * 4 + 3] * inv);
            *(ushort4*)(orow + db * 32 + qg * 8 + hi * 4) = pk;
        }
    }
}

// ---------------------------------------------------------------------------
// Output GEMM (m97 staging, proven): fp32 out. Same XCD-local token swizzle.
// ---------------------------------------------------------------------------
__global__ __launch_bounds__(256, 2)
void gemm_o(const unsigned short* __restrict__ W, const unsigned short* __restrict__ X,
            const float* __restrict__ bias, float* __restrict__ Cout)
{
    __shared__ unsigned short Ws[128][32];
    __shared__ unsigned short Xs[128][32];

    const int tid  = threadIdx.x;
    const int bx   = blockIdx.x, by = blockIdx.y;
    const int f0   = (by >> 3) * 128;
    const int t0   = ((bx << 3) | (by & 7)) * 128;
    const int lane = tid & 63, m = lane & 15, quad = lane >> 4;
    const int wid  = tid >> 6;
    const int wf   = (wid & 1) * 64;
    const int wt   = (wid >> 1) * 64;

    const int r    = tid >> 2, cc = tid & 3, sw = (tid >> 4) & 3;
    const int gcol = (cc ^ sw) << 3;
    const unsigned short* Wp = W + (size_t)(f0 + r) * EMBED + gcol;
    const unsigned short* Xp = X + (size_t)(t0 + r) * EMBED + gcol;
    unsigned short* WsL = &Ws[0][0] + tid * 8;
    unsigned short* XsL = &Xs[0][0] + tid * 8;

    const int qs = (quad ^ ((m >> 2) & 3)) << 3;

    f32x4 acc[4][4] = {};

    for (int k0 = 0; k0 < EMBED; k0 += 32) {
        __syncthreads();
        gload_lds16(Wp + k0,              WsL);
        gload_lds16(Wp + k0 + 64 * EMBED, WsL + 2048);
        gload_lds16(Xp + k0,              XsL);
        gload_lds16(Xp + k0 + 64 * EMBED, XsL + 2048);
        __syncthreads();

        short8 af[4], bf4[4];
#pragma unroll
        for (int mb = 0; mb < 4; ++mb)
            af[mb] = *(const short8*)&Ws[wf + mb * 16 + m][qs];
#pragma unroll
        for (int nb = 0; nb < 4; ++nb)
            bf4[nb] = *(const short8*)&Xs[wt + nb * 16 + m][qs];
#pragma unroll
        for (int mb = 0; mb < 4; ++mb)
#pragma unroll
            for (int nb = 0; nb < 4; ++nb)
                acc[mb][nb] = __builtin_amdgcn_mfma_f32_16x16x32_bf16(
                    af[mb], bf4[nb], acc[mb][nb], 0, 0, 0);
    }

#pragma unroll
    for (int mb = 0; mb < 4; ++mb) {
        const int feat = f0 + wf + mb * 16 + quad * 4;
        float4 bv4 = *(const float4*)&bias[feat];
#pragma unroll
        for (int nb = 0; nb < 4; ++nb) {
            const int tok = t0 + wt + nb * 16 + m;
            float4 st;
            st.x = acc[mb][nb][0] + bv4.x;
            st.y = acc[mb][nb][1] + bv4.y;
            st.z = acc[mb][nb][2] + bv4.z;
            st.w = acc[mb][nb][3] + bv4.w;
            *(float4*)(Cout + (size_t)tok * EMBED + feat) = st;
        }
    }
}

// ---------------------------------------------------------------------------
extern "C" void kernel_launch(void* const* d_in, const int* in_sizes, int n_in,
                              void* d_out, int out_size, void* d_ws, size_t ws_size,
                              hipStream_t stream)
{
    const float* x    = (const float*)d_in[0];
    const int*   mask = (const int*)  d_in[1];
    const float* Wq   = (const float*)d_in[2];
    const float* bq   = (const float*)d_in[3];
    const float* Wk   = (const float*)d_in[4];
    const float* bk   = (const float*)d_in[5];
    const float* Wv   = (const float*)d_in[6];
    const float* bv   = (const float*)d_in[7];
    const float* Wo   = (const float*)d_in[8];
    const float* bo   = (const float*)d_in[9];
    float* out = (float*)d_out;

    const size_t NE = (size_t)NTOK * EMBED;
    const size_t WE = (size_t)EMBED * EMBED;
    unsigned short* Xb  = (unsigned short*)d_ws;
    unsigned short* Wqb = Xb + NE;            // Wq,Wk,Wv,Wo contiguous
    unsigned short* Wob = Wqb + 3 * WE;
    unsigned short* Qw  = Wob + WE;
    unsigned short* Kw  = Qw + NE;
    unsigned short* VtG = Kw + NE;            // [b*H+h][d][s], d = 0..63
    unsigned short* Ow  = Xb;                 // reuse: Xb dead after projections

    cast_all<<<4096 + 2048, 256, 0, stream>>>(x, Wq, Wk, Wv, Wo, Xb, Wqb);

    gemm_qkv<<<dim3(8, 64), 256, 0, stream>>>(Xb, Wqb, bq, bk, bv, Qw, Kw, VtG);

    attn_mfma<<<BATCH * HEADS * (SEQ / 128), 256, 0, stream>>>(Qw, Kw, VtG, mask, Ow);

    gemm_o<<<dim3(8, 64), 256, 0, stream>>>(Wob, Ow, bo, out);
}

// Round 3
// 272.901 us; speedup vs baseline: 1.1403x; 1.0158x over previous
//
#include <hip/hip_runtime.h>

#define BATCH 4
#define SEQ   2048
#define EMBED 1024
#define HEADS 16
#define HDIM  64
#define NTOK  (BATCH*SEQ)

typedef __attribute__((ext_vector_type(8)))  short short8;   // 8 bf16 = MFMA A/B frag
typedef __attribute__((ext_vector_type(4)))  float f32x4;    // 16x16 C frag
typedef __attribute__((ext_vector_type(16))) float f32x16;   // 32x32 C frag

static __device__ __forceinline__ unsigned short f2bf(float f) {
    union { float f; unsigned u; } v; v.f = f;
    return (unsigned short)((v.u + 0x7FFFu + ((v.u >> 16) & 1u)) >> 16);  // RNE
}
// pack two floats -> bf16x2: single-instr HW convert (RNE), lo -> low 16
static __device__ __forceinline__ unsigned cvtpk(float lo, float hi) {
    unsigned r;
    asm("v_cvt_pk_bf16_f32 %0, %1, %2" : "=v"(r) : "v"(lo), "v"(hi));
    return r;
}
static __device__ __forceinline__ void gload_lds16(const unsigned short* g, unsigned short* l) {
    __builtin_amdgcn_global_load_lds(
        (__attribute__((address_space(1))) void*)g,
        (__attribute__((address_space(3))) void*)l, 16, 0, 0);
}

#define SCQ 0.180336880f   // log2(e)/8, folded into Q projection

// ---------------------------------------------------------------------------
// All fp32->bf16 casts in one launch: blocks [0,4096) = x, then 4x512 = weights
// ---------------------------------------------------------------------------
__global__ void cast_all(const float* __restrict__ x,
                         const float* __restrict__ w0, const float* __restrict__ w1,
                         const float* __restrict__ w2, const float* __restrict__ w3,
                         unsigned short* __restrict__ xb,
                         unsigned short* __restrict__ wb)
{
    const int bid = blockIdx.x;
    const float* src;
    unsigned short* dst;
    int i;
    if (bid < 4096) {
        src = x; dst = xb; i = (bid * 256 + threadIdx.x) * 8;
    } else {
        const int wz = (bid - 4096) >> 9;
        const float* ws[4] = {w0, w1, w2, w3};
        src = ws[wz];
        dst = wb + (size_t)wz * (EMBED * EMBED);
        i = (((bid - 4096) & 511) * 256 + threadIdx.x) * 8;
    }
    float4 a = *(const float4*)(src + i);
    float4 b = *(const float4*)(src + i + 4);
    union { int4 v; unsigned short u[8]; } pk;
    pk.u[0] = f2bf(a.x); pk.u[1] = f2bf(a.y); pk.u[2] = f2bf(a.z); pk.u[3] = f2bf(a.w);
    pk.u[4] = f2bf(b.x); pk.u[5] = f2bf(b.y); pk.u[6] = f2bf(b.z); pk.u[7] = f2bf(b.w);
    *(int4*)(dst + i) = pk.v;
}

// ---------------------------------------------------------------------------
// Fused QKV GEMM (m97 staging, proven): X staged ONCE per k-step, 3 weight
// tiles staged alongside -> 48 MFMA per 8 gloads. Outputs:
//   z0: Q row-major, pre-scaled by SCQ.  z1: K row-major.
//   z2: V transposed into VtG[bh][d][s] (no masking -- mask folded into attn).
// XCD swizzle: linear dispatch id = by*8+bx -> XCD = bx; give each XCD a
// contiguous 1024-token slice (2 MB, L2-resident) across all feature blocks.
// ---------------------------------------------------------------------------
__global__ __launch_bounds__(256, 2)
void gemm_qkv(const unsigned short* __restrict__ Xb,
              const unsigned short* __restrict__ Wall,
              const float* __restrict__ bq, const float* __restrict__ bk,
              const float* __restrict__ bv,
              unsigned short* __restrict__ Qw, unsigned short* __restrict__ Kw,
              unsigned short* __restrict__ VtG)
{
    __shared__ unsigned short Ws[3][128][32];
    __shared__ unsigned short Xs[128][32];

    const int tid  = threadIdx.x;
    const int bx   = blockIdx.x, by = blockIdx.y;
    const int f0   = (by >> 3) * 128;                  // feature block 0..7
    const int t0   = ((bx << 3) | (by & 7)) * 128;     // token block: XCD-local
    const int lane = tid & 63, m = lane & 15, quad = lane >> 4;
    const int wid  = tid >> 6;
    const int wf   = (wid & 1) * 64;
    const int wt   = (wid >> 1) * 64;

    const int r    = tid >> 2, cc = tid & 3, sw = (tid >> 4) & 3;
    const int gcol = (cc ^ sw) << 3;
    const unsigned short* Xp = Xb + (size_t)(t0 + r) * EMBED + gcol;
    const unsigned short* Wp = Wall + (size_t)(f0 + r) * EMBED + gcol;
    unsigned short* XsL = &Xs[0][0] + tid * 8;
    unsigned short* WsL = &Ws[0][0][0] + tid * 8;

    const int qs = (quad ^ ((m >> 2) & 3)) << 3;

    f32x4 aq[4][4] = {}, ak[4][4] = {}, av[4][4] = {};

    for (int k0 = 0; k0 < EMBED; k0 += 32) {
        __syncthreads();
        gload_lds16(Xp + k0,              XsL);
        gload_lds16(Xp + k0 + 64 * EMBED, XsL + 2048);
#pragma unroll
        for (int z = 0; z < 3; ++z) {
            const unsigned short* wz = Wp + (size_t)z * EMBED * EMBED + k0;
            gload_lds16(wz,              WsL + z * 4096);
            gload_lds16(wz + 64 * EMBED, WsL + z * 4096 + 2048);
        }
        __syncthreads();

        short8 bf4[4];
#pragma unroll
        for (int nb = 0; nb < 4; ++nb)
            bf4[nb] = *(const short8*)&Xs[wt + nb * 16 + m][qs];

#pragma unroll
        for (int z = 0; z < 3; ++z) {
            short8 af[4];
#pragma unroll
            for (int mb = 0; mb < 4; ++mb)
                af[mb] = *(const short8*)&Ws[z][wf + mb * 16 + m][qs];
            f32x4 (&acc)[4][4] = (z == 0) ? aq : (z == 1) ? ak : av;
#pragma unroll
            for (int mb = 0; mb < 4; ++mb)
#pragma unroll
                for (int nb = 0; nb < 4; ++nb)
                    acc[mb][nb] = __builtin_amdgcn_mfma_f32_16x16x32_bf16(
                        af[mb], bf4[nb], acc[mb][nb], 0, 0, 0);
        }
    }

    // ---- Q epilogue (scaled by SCQ) ----
#pragma unroll
    for (int mb = 0; mb < 4; ++mb) {
        const int feat = f0 + wf + mb * 16 + quad * 4;
        float4 bv4 = *(const float4*)&bq[feat];
#pragma unroll
        for (int nb = 0; nb < 4; ++nb) {
            const int tok = t0 + wt + nb * 16 + m;
            ushort4 pk;
            pk.x = f2bf((aq[mb][nb][0] + bv4.x) * SCQ);
            pk.y = f2bf((aq[mb][nb][1] + bv4.y) * SCQ);
            pk.z = f2bf((aq[mb][nb][2] + bv4.z) * SCQ);
            pk.w = f2bf((aq[mb][nb][3] + bv4.w) * SCQ);
            *(ushort4*)(Qw + (size_t)tok * EMBED + feat) = pk;
        }
    }
    // ---- K epilogue ----
#pragma unroll
    for (int mb = 0; mb < 4; ++mb) {
        const int feat = f0 + wf + mb * 16 + quad * 4;
        float4 bv4 = *(const float4*)&bk[feat];
#pragma unroll
        for (int nb = 0; nb < 4; ++nb) {
            const int tok = t0 + wt + nb * 16 + m;
            ushort4 pk;
            pk.x = f2bf(ak[mb][nb][0] + bv4.x);
            pk.y = f2bf(ak[mb][nb][1] + bv4.y);
            pk.z = f2bf(ak[mb][nb][2] + bv4.z);
            pk.w = f2bf(ak[mb][nb][3] + bv4.w);
            *(ushort4*)(Kw + (size_t)tok * EMBED + feat) = pk;
        }
    }
    // ---- V epilogue: transposed, unmasked ----
    {
        const int h = (f0 + wf) >> 6;              // feat block is h-aligned (64)
#pragma unroll
        for (int nb = 0; nb < 4; ++nb) {
            const int tok = t0 + wt + nb * 16 + m;
            const int b   = tok >> 11;
            const int s   = tok & (SEQ - 1);
            const size_t base = ((size_t)(b * HEADS + h) * HDIM) * SEQ + s;
#pragma unroll
            for (int mb = 0; mb < 4; ++mb) {
                const int feat  = f0 + wf + mb * 16 + quad * 4;
                const int dbase = mb * 16 + quad * 4;
                float4 bv4 = *(const float4*)&bv[feat];
                VtG[base + (size_t)(dbase + 0) * SEQ] = f2bf(av[mb][nb][0] + bv4.x);
                VtG[base + (size_t)(dbase + 1) * SEQ] = f2bf(av[mb][nb][1] + bv4.y);
                VtG[base + (size_t)(dbase + 2) * SEQ] = f2bf(av[mb][nb][2] + bv4.z);
                VtG[base + (size_t)(dbase + 3) * SEQ] = f2bf(av[mb][nb][3] + bv4.w);
            }
        }
    }
}

// ---------------------------------------------------------------------------
// MFMA flash attention, 32x32x16. PROVEN two-barrier single-buffer schedule.
// R2 post-mortem: issue-slot bound (MfmaUtil 35 + VALUBusy 48 = 83%), so R3
// moves softmax-finish work off the VALU:
//  - denominator via 4th PV MFMA with CONSTANT all-ones A-frag (masked p are
//    exactly 0 from the mask-fold, so plain sum = masked sum). Kills the
//    32-add lr tree + final shfl; inv = 1/o2[0].
//  - v_cvt_pk_bf16_f32 (1 instr) replaces 3-instr pk2bf.          (T12)
//  - v_permlane32_swap_b32 replaces shfl_xor+select exchange:
//    swap(D0,D2) = (fr.x, fr.z), swap(D1,D3) = (fr.y, fr.w).      (T12)
// ---------------------------------------------------------------------------
__global__ __launch_bounds__(256, 4)
void attn_mfma(const unsigned short* __restrict__ Qb,
               const unsigned short* __restrict__ Kb,
               const unsigned short* __restrict__ VtG,
               const int* __restrict__ mask,
               unsigned short* __restrict__ Ob)
{
    __shared__ unsigned short Ks[64][72];     // [key][d]
    __shared__ unsigned short Vs[64][72];     // [d][key]

    const int tid  = threadIdx.x;
    // XCD-local remap: XCD = blockIdx.x % 8 gets 8 contiguous (b,h) groups
    const int lin  = (blockIdx.x & 7) * 128 + (blockIdx.x >> 3);
    const int qb   = lin & 15;
    const int h    = (lin >> 4) & 15;
    const int b    = lin >> 8;
    const int wid  = tid >> 6, lane = tid & 63;
    const int q32  = lane & 31, hi = lane >> 5;
    const int tb   = b * SEQ;
    const int q    = qb * 128 + wid * 32 + q32;

    // Q B-frags (pre-scaled): k = st*16 + hi*8 + j
    const unsigned short* qrow = Qb + (size_t)(tb + q) * EMBED + h * HDIM;
    short8 qf[4];
#pragma unroll
    for (int st = 0; st < 4; ++st)
        qf[st] = *(const short8*)(qrow + st * 16 + hi * 8);

    // mask B-frag: B[q][k]: nonzero only at k==0 (lanes hi==0, j==0)
    short8 mqf = {0, 0, 0, 0, 0, 0, 0, 0};
    mqf[0] = hi ? (short)0 : (short)0xC480;   // bf16(-1024), exact

    // all-ones A-frag for the denominator MFMA (every C row = sum_k P[k][q])
    short8 onef;
#pragma unroll
    for (int j = 0; j < 8; ++j) onef[j] = (short)0x3F80;

    f32x16 o0, o1, o2, z16;
#pragma unroll
    for (int i = 0; i < 16; ++i) { z16[i] = 0.f; }
    o0 = z16; o1 = z16; o2 = z16;

    // staging: thread -> (row = tid>>2, 16-elem col group = (tid&3)*16)
    const int sr = tid >> 2, sc = (tid & 3) * 16;
    const unsigned short* kSrc = Kb + (size_t)(tb + sr) * EMBED + h * HDIM + sc;
    const unsigned short* vSrc = VtG + ((size_t)(b * HEADS + h) * HDIM + sr) * SEQ + sc;
    const int* mrow = mask + b * SEQ;

    for (int kt = 0; kt < SEQ; kt += 64) {
        // loads for THIS tile at loop top; cross-block TLP hides the latency
        int4 kv0 = *(const int4*)(kSrc + (size_t)kt * EMBED);
        int4 kv1 = *(const int4*)(kSrc + (size_t)kt * EMBED + 8);
        int4 vv0 = *(const int4*)(vSrc + kt);
        int4 vv1 = *(const int4*)(vSrc + kt + 8);
        const int mva = mrow[kt + q32];
        const int mvb = mrow[kt + 32 + q32];
        __syncthreads();
        *(int4*)&Ks[sr][sc]     = kv0;
        *(int4*)&Ks[sr][sc + 8] = kv1;
        *(int4*)&Vs[sr][sc]     = vv0;
        *(int4*)&Vs[sr][sc + 8] = vv1;
        __syncthreads();

        // mask A-frags: A[key][k]: nonzero only at k==0: maskbit = 1.0 if masked
        short8 mkfa = {0, 0, 0, 0, 0, 0, 0, 0};
        short8 mkfb = {0, 0, 0, 0, 0, 0, 0, 0};
        mkfa[0] = (hi == 0 && mva == 0) ? (short)0x3F80 : (short)0;
        mkfb[0] = (hi == 0 && mvb == 0) ? (short)0x3F80 : (short)0;

#pragma unroll
        for (int kb = 0; kb < 2; ++kb) {
            // S' = mask-bias + K·Q^T over 4 d-steps (Q pre-scaled -> exp2 domain)
            f32x16 s = __builtin_amdgcn_mfma_f32_32x32x16_bf16(
                kb ? mkfb : mkfa, mqf, z16, 0, 0, 0);
#pragma unroll
            for (int st = 0; st < 4; ++st) {
                short8 kf = *(const short8*)&Ks[kb * 32 + q32][st * 16 + hi * 8];
                s = __builtin_amdgcn_mfma_f32_32x32x16_bf16(kf, qf[st], s, 0, 0, 0);
            }

            // p = exp2(s); masked keys give exactly 0; pack via HW cvt_pk
            float p[16];
#pragma unroll
            for (int i = 0; i < 16; ++i) p[i] = __builtin_amdgcn_exp2f(s[i]);
            unsigned D[8];
#pragma unroll
            for (int j = 0; j < 8; ++j) D[j] = cvtpk(p[2 * j], p[2 * j + 1]);

            // PV over 2 chunks of 16 keys; B-frag via permlane32_swap:
            // swap(D0,D2) -> (fr.x, fr.z); swap(D1,D3) -> (fr.y, fr.w)
#pragma unroll
            for (int cl = 0; cl < 2; ++cl) {
                unsigned x0 = D[4 * cl + 0], x1 = D[4 * cl + 1];
                unsigned x2 = D[4 * cl + 2], x3 = D[4 * cl + 3];
                asm("v_permlane32_swap_b32 %0, %1" : "+v"(x0), "+v"(x2));
                asm("v_permlane32_swap_b32 %0, %1" : "+v"(x1), "+v"(x3));
                union { uint4 u; short8 s8; } fr;
                fr.u.x = x0; fr.u.y = x1; fr.u.z = x2; fr.u.w = x3;

                const int kcol = kb * 32 + cl * 16 + hi * 8;
                short8 vf0 = *(const short8*)&Vs[q32][kcol];
                short8 vf1 = *(const short8*)&Vs[32 + q32][kcol];
                o0 = __builtin_amdgcn_mfma_f32_32x32x16_bf16(vf0, fr.s8, o0, 0, 0, 0);
                o1 = __builtin_amdgcn_mfma_f32_32x32x16_bf16(vf1, fr.s8, o1, 0, 0, 0);
                o2 = __builtin_amdgcn_mfma_f32_32x32x16_bf16(onef, fr.s8, o2, 0, 0, 0);
            }
        }
    }

    // denominator: every o2 row = sum_k p (same value), col = this lane's q
    const float inv = 1.0f / o2[0];
    unsigned short* orow = Ob + (size_t)(tb + q) * EMBED + h * HDIM;
#pragma unroll
    for (int db = 0; db < 2; ++db) {
        const f32x16& oo = db ? o1 : o0;
#pragma unroll
        for (int qg = 0; qg < 4; ++qg) {
            ushort4 pk;
            pk.x = f2bf(oo[qg * 4 + 0] * inv);
            pk.y = f2bf(oo[qg * 4 + 1] * inv);
            pk.z = f2bf(oo[qg * 4 + 2] * inv);
            pk.w = f2bf(oo[qg * 4 + 3] * inv);
            *(ushort4*)(orow + db * 32 + qg * 8 + hi * 4) = pk;
        }
    }
}

// ---------------------------------------------------------------------------
// Output GEMM (m97 staging, proven): fp32 out. Same XCD-local token swizzle.
// ---------------------------------------------------------------------------
__global__ __launch_bounds__(256, 2)
void gemm_o(const unsigned short* __restrict__ W, const unsigned short* __restrict__ X,
            const float* __restrict__ bias, float* __restrict__ Cout)
{
    __shared__ unsigned short Ws[128][32];
    __shared__ unsigned short Xs[128][32];

    const int tid  = threadIdx.x;
    const int bx   = blockIdx.x, by = blockIdx.y;
    const int f0   = (by >> 3) * 128;
    const int t0   = ((bx << 3) | (by & 7)) * 128;
    const int lane = tid & 63, m = lane & 15, quad = lane >> 4;
    const int wid  = tid >> 6;
    const int wf   = (wid & 1) * 64;
    const int wt   = (wid >> 1) * 64;

    const int r    = tid >> 2, cc = tid & 3, sw = (tid >> 4) & 3;
    const int gcol = (cc ^ sw) << 3;
    const unsigned short* Wp = W + (size_t)(f0 + r) * EMBED + gcol;
    const unsigned short* Xp = X + (size_t)(t0 + r) * EMBED + gcol;
    unsigned short* WsL = &Ws[0][0] + tid * 8;
    unsigned short* XsL = &Xs[0][0] + tid * 8;

    const int qs = (quad ^ ((m >> 2) & 3)) << 3;

    f32x4 acc[4][4] = {};

    for (int k0 = 0; k0 < EMBED; k0 += 32) {
        __syncthreads();
        gload_lds16(Wp + k0,              WsL);
        gload_lds16(Wp + k0 + 64 * EMBED, WsL + 2048);
        gload_lds16(Xp + k0,              XsL);
        gload_lds16(Xp + k0 + 64 * EMBED, XsL + 2048);
        __syncthreads();

        short8 af[4], bf4[4];
#pragma unroll
        for (int mb = 0; mb < 4; ++mb)
            af[mb] = *(const short8*)&Ws[wf + mb * 16 + m][qs];
#pragma unroll
        for (int nb = 0; nb < 4; ++nb)
            bf4[nb] = *(const short8*)&Xs[wt + nb * 16 + m][qs];
#pragma unroll
        for (int mb = 0; mb < 4; ++mb)
#pragma unroll
            for (int nb = 0; nb < 4; ++nb)
                acc[mb][nb] = __builtin_amdgcn_mfma_f32_16x16x32_bf16(
                    af[mb], bf4[nb], acc[mb][nb], 0, 0, 0);
    }

#pragma unroll
    for (int mb = 0; mb < 4; ++mb) {
        const int feat = f0 + wf + mb * 16 + quad * 4;
        float4 bv4 = *(const float4*)&bias[feat];
#pragma unroll
        for (int nb = 0; nb < 4; ++nb) {
            const int tok = t0 + wt + nb * 16 + m;
            float4 st;
            st.x = acc[mb][nb][0] + bv4.x;
            st.y = acc[mb][nb][1] + bv4.y;
            st.z = acc[mb][nb][2] + bv4.z;
            st.w = acc[mb][nb][3] + bv4.w;
            *(float4*)(Cout + (size_t)tok * EMBED + feat) = st;
        }
    }
}

// ---------------------------------------------------------------------------
extern "C" void kernel_launch(void* const* d_in, const int* in_sizes, int n_in,
                              void* d_out, int out_size, void* d_ws, size_t ws_size,
                              hipStream_t stream)
{
    const float* x    = (const float*)d_in[0];
    const int*   mask = (const int*)  d_in[1];
    const float* Wq   = (const float*)d_in[2];
    const float* bq   = (const float*)d_in[3];
    const float* Wk   = (const float*)d_in[4];
    const float* bk   = (const float*)d_in[5];
    const float* Wv   = (const float*)d_in[6];
    const float* bv   = (const float*)d_in[7];
    const float* Wo   = (const float*)d_in[8];
    const float* bo   = (const float*)d_in[9];
    float* out = (float*)d_out;

    const size_t NE = (size_t)NTOK * EMBED;
    const size_t WE = (size_t)EMBED * EMBED;
    unsigned short* Xb  = (unsigned short*)d_ws;
    unsigned short* Wqb = Xb + NE;            // Wq,Wk,Wv,Wo contiguous
    unsigned short* Wob = Wqb + 3 * WE;
    unsigned short* Qw  = Wob + WE;
    unsigned short* Kw  = Qw + NE;
    unsigned short* VtG = Kw + NE;            // [b*H+h][d][s], d = 0..63
    unsigned short* Ow  = Xb;                 // reuse: Xb dead after projections

    cast_all<<<4096 + 2048, 256, 0, stream>>>(x, Wq, Wk, Wv, Wo, Xb, Wqb);

    gemm_qkv<<<dim3(8, 64), 256, 0, stream>>>(Xb, Wqb, bq, bk, bv, Qw, Kw, VtG);

    attn_mfma<<<BATCH * HEADS * (SEQ / 128), 256, 0, stream>>>(Qw, Kw, VtG, mask, Ow);

    gemm_o<<<dim3(8, 64), 256, 0, stream>>>(Wob, Ow, bo, out);
}